// Round 4
// baseline (410.974 us; speedup 1.0000x reference)
//
#include <hip/hip_runtime.h>

typedef unsigned short u16;
typedef float f32x4 __attribute__((ext_vector_type(4)));
typedef __bf16 bf16x8 __attribute__((ext_vector_type(8)));

#define T_ 4096
#define D_ 1024
#define NW_ 64

__device__ __forceinline__ float b2f(u16 u) {
  return __uint_as_float(((unsigned)u) << 16);
}
__device__ __forceinline__ u16 f2bf(float f) {
  unsigned u = __float_as_uint(f);
  u += 0x7fffu + ((u >> 16) & 1u);   // RNE
  return (u16)(u >> 16);
}
__device__ __forceinline__ void g2l16(const u16* g, u16* l) {
  __builtin_amdgcn_global_load_lds((const __attribute__((address_space(1))) void*)g,
                                   (__attribute__((address_space(3))) void*)l, 16, 0, 0);
}

// fused fp32->bf16 casts: x (16384 blk), Wqkv (3072 blk), Wcross (1024 blk)
__global__ __launch_bounds__(256) void cvt3_k(const float* __restrict__ s0, u16* __restrict__ d0,
                                              const float* __restrict__ s1, u16* __restrict__ d1,
                                              const float* __restrict__ s2, u16* __restrict__ d2)
{
  long bid = blockIdx.x;
  const float* src; u16* dst; long base;
  if (bid < 16384)      { src = s0; dst = d0; base = bid * 1024; }
  else if (bid < 19456) { src = s1; dst = d1; base = (bid - 16384) * 1024; }
  else                  { src = s2; dst = d2; base = (bid - 19456) * 1024; }
  long i = base + (long)threadIdx.x * 4;
  float4 v = *(const float4*)(src + i);
  ushort4 o;
  o.x = f2bf(v.x); o.y = f2bf(v.y); o.z = f2bf(v.z); o.w = f2bf(v.w);
  *(ushort4*)(dst + i) = o;
}

__global__ __launch_bounds__(256) void cvt_k(const float* __restrict__ src,
                                             u16* __restrict__ dst, long n)
{
  long i = ((long)blockIdx.x * 256 + threadIdx.x) * 4;
  if (i >= n) return;
  float4 v = *(const float4*)(src + i);
  ushort4 o;
  o.x = f2bf(v.x); o.y = f2bf(v.y); o.z = f2bf(v.z); o.w = f2bf(v.w);
  *(ushort4*)(dst + i) = o;
}

// C(M,N) = A(M,K;lda) @ B(N,K)^T [+ bias], A/B bf16, fp32 accum.
// 256x256 tile, BK=64, 512 thr (8 waves, 2x4). Read-ahead 8-phase schedule:
// each phase {issue NEXT phase's frag ds_reads into alternate bank | MFMA this
// phase | issue 1 half-tile stage | vmcnt(8)+barrier}. ONE barrier per phase;
// frag reads overlap MFMA across the CU. FIFO ledger (verified): steady state
// 8 loads outstanding after each wait, +2/phase; every read-bearing phase is
// preceded by a wait+barrier completing exactly the stripes it reads; stage(p)
// targets disjoint from reads-in-(p-1) U reads-in-p for all p. T2 LDS swizzle
// (linear gload_lds dest + inverse-swizzled global src), setprio around MFMA,
// bijective XCD blockIdx swizzle, LDS-staged coalesced epilogue.
// Requires M,N % 256 == 0, K % 128 == 0.
__global__ __launch_bounds__(512, 2) void gemm256(
    const u16* __restrict__ A, const u16* __restrict__ Bm,
    u16* __restrict__ C16, float* __restrict__ C32,
    const float* __restrict__ bias, int M, int N, int K, int lda)
{
  // one 128KB region: A stripes at [0,32K) u16, B stripes at [32K,64K) u16.
  // A stripe (buf,mh): rows rho=0..127 <-> global m0 + mh*64 + (rho&63) + (rho>>6)*128
  // B stripe (buf,nh): rows rho=0..127 <-> global n0 + nh*32 + (rho&31) + (rho>>5)*64
  // 16B slot s of row rho holds k-group (s ^ (rho&7))  [XOR swizzle, involution]
  __shared__ u16 SH[65536];
  (void)M;
  const int tid = threadIdx.x;
  const int lane = tid & 63;
  const int w = tid >> 6;
  const int wm = w >> 2, wn = w & 3;
  const int q = lane >> 4, il = lane & 15;

  // XCD-aware bijective chunked swizzle (nwg % 8 == 0 for all our grids)
  const int nbx = gridDim.x;
  const int nwg = nbx * (int)gridDim.y;
  const int bid = (int)blockIdx.y * nbx + (int)blockIdx.x;
  const int nid = (bid & 7) * (nwg >> 3) + (bid >> 3);
  const long m0 = (long)(nid / nbx) * 256;
  const long n0 = (long)(nid % nbx) * 256;

  const int nt = K >> 6;               // # K-tiles, even (K % 128 == 0)
  const int ntm1 = nt - 1;

  // staging constants: 2 load-units per stripe per thread (u = i*512 + tid)
  const int u0 = tid, u1 = 512 + tid;
  const int r0 = u0 >> 3, r1 = u1 >> 3;
  const int sx0 = ((u0 & 7) ^ (r0 & 7)) << 3;   // pre-swizzled source k-offset (elems)
  const int sx1 = ((u1 & 7) ^ (r1 & 7)) << 3;
  const long gar0 = m0 + (r0 >> 6) * 128 + (r0 & 63);
  const long gar1 = m0 + (r1 >> 6) * 128 + (r1 & 63);
  const long gbr0 = n0 + (r0 >> 5) * 64 + (r0 & 31);
  const long gbr1 = n0 + (r1 >> 5) * 64 + (r1 & 31);
  const int dl = w * 512;              // wave-uniform LDS dest (u16), HW adds lane*16B

  // fragment read constants (swizzled k-slot = slot ^ (row&7))
  const int aro = (wm * 64 + il) * 64;
  const int bro = (wn * 32 + il) * 64;
  const int ax = (il & 7) << 3;
  const int ko0 = (q * 8) ^ ax;        // kk=0
  const int ko1 = (32 + q * 8) ^ ax;   // kk=1

  f32x4 acc[8][4] = {};
  bf16x8 afA[4][2], afB[4][2], bf0[2][2], bf1[2][2];   // ping-pong frag banks

#define ASP(BUF, MH) (&SH[((BUF) * 2 + (MH)) * 8192])
#define BSP(BUF, NH) (&SH[32768 + ((BUF) * 2 + (NH)) * 8192])
#define STGA(BUF, MH, KT) do { \
    g2l16(A + (gar0 + (MH) * 64) * (long)lda + (KT) * 64 + sx0, ASP(BUF, MH) + dl); \
    g2l16(A + (gar1 + (MH) * 64) * (long)lda + (KT) * 64 + sx1, ASP(BUF, MH) + 4096 + dl); \
  } while (0)
#define STGB(BUF, NH, KT) do { \
    g2l16(Bm + (gbr0 + (NH) * 32) * (long)K + (KT) * 64 + sx0, BSP(BUF, NH) + dl); \
    g2l16(Bm + (gbr1 + (NH) * 32) * (long)K + (KT) * 64 + sx1, BSP(BUF, NH) + 4096 + dl); \
  } while (0)
#define LDAF(BUF, MH, AF) do { \
    _Pragma("unroll") for (int f = 0; f < 4; ++f) { \
      AF[f][0] = *(const bf16x8*)(ASP(BUF, MH) + aro + f * 1024 + ko0); \
      AF[f][1] = *(const bf16x8*)(ASP(BUF, MH) + aro + f * 1024 + ko1); \
    } } while (0)
#define LDBF(BUF, NH, BF) do { \
    _Pragma("unroll") for (int j = 0; j < 2; ++j) { \
      BF[j][0] = *(const bf16x8*)(BSP(BUF, NH) + bro + j * 1024 + ko0); \
      BF[j][1] = *(const bf16x8*)(BSP(BUF, NH) + bro + j * 1024 + ko1); \
    } } while (0)
#define MFMAQ(MH, NH, AF, BF) do { \
    _Pragma("unroll") for (int f = 0; f < 4; ++f) { \
      _Pragma("unroll") for (int j = 0; j < 2; ++j) { \
        acc[(MH)*4+f][(NH)*2+j] = __builtin_amdgcn_mfma_f32_16x16x32_bf16(AF[f][0], BF[j][0], acc[(MH)*4+f][(NH)*2+j], 0, 0, 0); \
        acc[(MH)*4+f][(NH)*2+j] = __builtin_amdgcn_mfma_f32_16x16x32_bf16(AF[f][1], BF[j][1], acc[(MH)*4+f][(NH)*2+j], 0, 0, 0); \
      } } } while (0)
#define BARR() __builtin_amdgcn_s_barrier()
#define WV8() asm volatile("s_waitcnt vmcnt(8)" ::: "memory")
#define PRIO(x) __builtin_amdgcn_s_setprio(x)

  // prologue: pro1..pro7 = [A0b0,B0b0,B1b0,A1b0 | A0b1,B0b1,B1b1] (t0,t0,t0,t0,t1,t1,t1)
  // WV8 completes pro1-3 -> pre-loop reads (A0b0,B0b0) + P1's read (B1b0) covered.
  STGA(0, 0, 0); STGB(0, 0, 0); STGB(0, 1, 0); STGA(0, 1, 0);
  STGA(1, 0, 1); STGB(1, 0, 1); STGB(1, 1, 1);
  WV8();
  BARR();
  LDAF(0, 0, afA); LDBF(0, 0, bf0);    // frags for P1 (tile 0, Q(0,0))

  for (int tt = 0; tt < nt; tt += 2) {
    const int t1 = tt + 1;
    const int t2 = tt + 2 <= ntm1 ? tt + 2 : ntm1;  // tail: valid addr, dead data
    const int t3 = tt + 3 <= ntm1 ? tt + 3 : ntm1;
    // P1: MFMA(0,0)[afA,bf0]; read bf1<-B1b0(tt); s1=A1b1(t1); wait covers A1b0
    LDBF(0, 1, bf1);
    PRIO(1); MFMAQ(0, 0, afA, bf0); PRIO(0);
    STGA(1, 1, t1);
    WV8(); BARR();
    // P2: MFMA(0,1)[afA,bf1]; read afB<-A1b0(tt); s2=A0b0(t2)
    LDAF(0, 1, afB);
    PRIO(1); MFMAQ(0, 1, afA, bf1); PRIO(0);
    STGA(0, 0, t2);
    BARR();
    // P3: MFMA(1,0)[afB,bf0]; s3=B0b0(t2); wait covers A0b1,B0b1
    PRIO(1); MFMAQ(1, 0, afB, bf0); PRIO(0);
    STGB(0, 0, t2);
    WV8(); BARR();
    // P4: MFMA(1,1)[afB,bf1]; read afA<-A0b1, bf0<-B0b1 (tt+1); s4=B1b0(t2); wait covers B1b1
    LDAF(1, 0, afA); LDBF(1, 0, bf0);
    PRIO(1); MFMAQ(1, 1, afB, bf1); PRIO(0);
    STGB(0, 1, t2);
    WV8(); BARR();
    // P5: tile tt+1 MFMA(0,0)[afA,bf0]; read bf1<-B1b1; s5=A1b0(t2); wait covers A1b1
    LDBF(1, 1, bf1);
    PRIO(1); MFMAQ(0, 0, afA, bf0); PRIO(0);
    STGA(0, 1, t2);
    WV8(); BARR();
    // P6: MFMA(0,1)[afA,bf1]; read afB<-A1b1; s6=A0b1(t3)
    LDAF(1, 1, afB);
    PRIO(1); MFMAQ(0, 1, afA, bf1); PRIO(0);
    STGA(1, 0, t3);
    BARR();
    // P7: MFMA(1,0)[afB,bf0]; s7=B0b1(t3); wait covers A0b0,B0b0 (t2)
    PRIO(1); MFMAQ(1, 0, afB, bf0); PRIO(0);
    STGB(1, 0, t3);
    WV8(); BARR();
    // P8: MFMA(1,1)[afB,bf1]; read afA<-A0b0, bf0<-B0b0 (tt+2); s8=B1b1(t3); wait covers B1b0(t2)
    LDAF(0, 0, afA); LDBF(0, 0, bf0);
    PRIO(1); MFMAQ(1, 1, afB, bf1); PRIO(0);
    STGB(1, 1, t3);
    WV8(); BARR();
  }

  asm volatile("s_waitcnt vmcnt(0)" ::: "memory");  // drain tail stages (they DMA into SH)
  __syncthreads();

  // ---- epilogue: stage C tile in LDS, emit full-line coalesced stores ----
  if (C32) {
    // fp32: two 128-row halves (128*256*4B = 128KB each). wm==h waves own half h.
    float* Cf = (float*)SH;
#pragma unroll
    for (int h = 0; h < 2; ++h) {
      if (wm == h) {
#pragma unroll
        for (int ni = 0; ni < 4; ++ni) {
          const int ccol = wn * 64 + ni * 16 + il;
          const float bv = bias ? bias[n0 + ccol] : 0.0f;
#pragma unroll
          for (int mi = 0; mi < 8; ++mi) {
#pragma unroll
            for (int r = 0; r < 4; ++r) {
              const int crow = (mi >> 2) * 64 + (mi & 3) * 16 + q * 4 + r;
              const int byte = (crow * 1024 + ccol * 4) ^ (((crow >> 2) & 1) << 6);
              *(float*)((char*)Cf + byte) = acc[mi][ni][r] + bv;
            }
          }
        }
      }
      __syncthreads();
#pragma unroll
      for (int i = 0; i < 16; ++i) {
        const int u = i * 512 + tid;
        const int crow = u >> 6, c16 = u & 63;
        const int byte = (crow * 1024 + c16 * 16) ^ (((crow >> 2) & 1) << 6);
        float4 v = *(const float4*)((char*)Cf + byte);
        *(float4*)(C32 + (m0 + h * 128 + crow) * N + n0 + c16 * 4) = v;
      }
      __syncthreads();
    }
  } else {
    // bf16: whole 256x256 tile = 128KB.
    u16* Cs = (u16*)SH;
#pragma unroll
    for (int ni = 0; ni < 4; ++ni) {
      const int ccol = wn * 64 + ni * 16 + il;
      const float bv = bias ? bias[n0 + ccol] : 0.0f;
#pragma unroll
      for (int mi = 0; mi < 8; ++mi) {
#pragma unroll
        for (int r = 0; r < 4; ++r) {
          const int crow = wm * 128 + (mi >> 2) * 64 + (mi & 3) * 16 + q * 4 + r;
          const int byte = (crow * 512 + ccol * 2) ^ (((crow >> 2) & 3) << 5);
          *(u16*)((char*)Cs + byte) = f2bf(acc[mi][ni][r] + bv);
        }
      }
    }
    __syncthreads();
#pragma unroll
    for (int i = 0; i < 16; ++i) {
      const int u = i * 512 + tid;
      const int crow = u >> 5, c16 = u & 31;
      const int byte = (crow * 512 + c16 * 16) ^ (((crow >> 2) & 3) << 5);
      uint4 v = *(const uint4*)((char*)Cs + byte);
      *(uint4*)(C16 + (m0 + crow) * N + n0 + c16 * 8) = v;
    }
  }
#undef ASP
#undef BSP
#undef STGA
#undef STGB
#undef LDAF
#undef LDBF
#undef MFMAQ
#undef BARR
#undef WV8
#undef PRIO
}

// scores[r] = mean(tanh(y[r, :])) over D=1024 (y bf16, bias already added)
__global__ __launch_bounds__(256) void scores_k(const u16* __restrict__ y,
                                                float* __restrict__ scores)
{
  const int lane = threadIdx.x & 63;
  const long r = (long)blockIdx.x * 4 + (threadIdx.x >> 6);
  const u16* p = y + r * D_ + lane * 16;
  uint4 v0 = *(const uint4*)p;
  uint4 v1 = *(const uint4*)(p + 8);
  union { uint4 v; u16 s[8]; } a, c;
  a.v = v0; c.v = v1;
  float s = 0.f;
#pragma unroll
  for (int e = 0; e < 8; ++e) s += tanhf(b2f(a.s[e]));
#pragma unroll
  for (int e = 0; e < 8; ++e) s += tanhf(b2f(c.s[e]));
#pragma unroll
  for (int o = 32; o; o >>= 1) s += __shfl_xor(s, o, 64);
  if (lane == 0) scores[r] = s * (1.0f / 1024.0f);
}

// per-window softmax over scores -> weighted sum of fp32 x rows -> summaries
__global__ __launch_bounds__(256) void summar_k(const float* __restrict__ x,
                                                const float* __restrict__ scores,
                                                float* __restrict__ summ)
{
  __shared__ float wts[64];
  const int tid = threadIdx.x;
  const int b = blockIdx.x >> 6, n = blockIdx.x & 63;
  if (tid < 64) {
    float v = scores[(long)b * T_ + n * 64 + tid];
    float mx = v;
#pragma unroll
    for (int o = 32; o; o >>= 1) mx = fmaxf(mx, __shfl_xor(mx, o, 64));
    float e = __expf(v - mx);
    float s = e;
#pragma unroll
    for (int o = 32; o; o >>= 1) s += __shfl_xor(s, o, 64);
    wts[tid] = e / s;
  }
  __syncthreads();
  const int d0 = tid * 4;
  const float* xp = x + ((long)b * T_ + n * 64) * D_ + d0;
  float a0 = 0, a1 = 0, a2 = 0, a3 = 0;
#pragma unroll 4
  for (int wd = 0; wd < 64; ++wd) {
    float4 v = *(const float4*)(xp + (long)wd * D_);
    float wv = wts[wd];
    a0 += wv * v.x; a1 += wv * v.y; a2 += wv * v.z; a3 += wv * v.w;
  }
  *(float4*)(summ + ((long)b * NW_ + n) * D_ + d0) = make_float4(a0, a1, a2, a3);
}

// cross-summary attention: cs_out[b,n,:] = softmax(summ[n]·jit[m]/32)_m @ jit
__global__ __launch_bounds__(256) void cross_k(const float* __restrict__ summ,
                                               const int* __restrict__ jitter,
                                               float* __restrict__ cso)
{
  __shared__ float sm[64], pm[64];
  __shared__ int jidx[64];
  const int tid = threadIdx.x;
  const int b = blockIdx.x >> 6, n = blockIdx.x & 63;
  if (tid < 64) jidx[tid] = jitter[tid];
  __syncthreads();
  const int m = tid >> 2, part = tid & 3;
  const float* sn = summ + ((long)b * NW_ + n) * D_;
  const float* sj = summ + ((long)b * NW_ + jidx[m]) * D_;
  float p = 0.f;
  for (int d = part * 256; d < part * 256 + 256; d += 4) {
    float4 aa = *(const float4*)(sn + d);
    float4 bb = *(const float4*)(sj + d);
    p += aa.x * bb.x + aa.y * bb.y + aa.z * bb.z + aa.w * bb.w;
  }
  p += __shfl_xor(p, 1, 64);
  p += __shfl_xor(p, 2, 64);
  if (part == 0) sm[m] = p * (1.0f / 32.0f);
  __syncthreads();
  if (tid < 64) {
    float v = sm[tid], mx = v;
#pragma unroll
    for (int o = 32; o; o >>= 1) mx = fmaxf(mx, __shfl_xor(mx, o, 64));
    float e = __expf(v - mx), s = e;
#pragma unroll
    for (int o = 32; o; o >>= 1) s += __shfl_xor(s, o, 64);
    pm[tid] = e / s;
  }
  __syncthreads();
  const int d0 = tid * 4;
  float a0 = 0, a1 = 0, a2 = 0, a3 = 0;
  for (int mm = 0; mm < 64; ++mm) {
    const float* sr = summ + ((long)b * NW_ + jidx[mm]) * D_ + d0;
    float wv = pm[mm];
    float4 vv = *(const float4*)sr;
    a0 += wv * vv.x; a1 += wv * vv.y; a2 += wv * vv.z; a3 += wv * vv.w;
  }
  *(float4*)(cso + ((long)b * NW_ + n) * D_ + d0) = make_float4(a0, a1, a2, a3);
}

// windowed attention, one block per (b,h,n); writes final = local + 0.25*cs
// IN-PLACE into the q-slice of qkv (each block writes only the region it reads).
__global__ __launch_bounds__(256) void attn_win(u16* qkv,
                                                const float* __restrict__ cso)
{
  __shared__ u16 Qs[64 * 72], Ks[64 * 72], Vt[64 * 72], Ps[64 * 72];
  unsigned* Vt32 = (unsigned*)Vt;          // word stride 36/row (byte 144, b128-aligned)
  const int tid = threadIdx.x;
  const int lane = tid & 63;
  const int w = tid >> 6;
  const int q = lane >> 4, il = lane & 15;
  const int bid = blockIdx.x;
  const int n = bid & 63;
  const int h = (bid >> 6) & 15;
  const int b = bid >> 10;
  const long rowbase = (long)b * T_ + n * 64;

#pragma unroll
  for (int i = 0; i < 2; ++i) {
    int u = i * 256 + tid;
    int row = u >> 3, cp = u & 7;
    const u16* src = qkv + (rowbase + row) * 3072 + h * 64 + cp * 8;
    uint4 qv = *(const uint4*)src;
    uint4 kv = *(const uint4*)(src + 1024);
    uint4 vv = *(const uint4*)(src + 2048);
    *(uint4*)&Qs[row * 72 + cp * 8] = qv;
    *(uint4*)&Ks[row * 72 + cp * 8] = kv;
    // V transpose via row-pair packing: tid/tid^8 hold rows 2p,2p+1 (same cols).
    union { uint4 v; unsigned u[4]; } mine, part;
    mine.v = vv;
#pragma unroll
    for (int m = 0; m < 4; ++m) part.u[m] = __shfl_xor(mine.u[m], 8, 64);
    const bool even = ((row & 1) == 0);
    const int p = row >> 1;
#pragma unroll
    for (int m = 0; m < 4; ++m) {
      unsigned word = even ? ((mine.u[m] & 0xffffu) | (part.u[m] << 16))
                           : ((part.u[m] >> 16)     | (mine.u[m] & 0xffff0000u));
      int c = cp * 8 + 2 * m + (even ? 0 : 1);     // Vt row = V column
      Vt32[c * 36 + p] = word;                     // u32 store: 4 stores vs 8, ~8-way
    }
  }
  __syncthreads();

  // S = Q K^T : wave w owns rows [16w,16w+16), 4 col-tiles of 16
  f32x4 sacc[4] = {};
#pragma unroll
  for (int ks = 0; ks < 2; ++ks) {
    bf16x8 aq = *(const bf16x8*)&Qs[(w * 16 + il) * 72 + ks * 32 + q * 8];
#pragma unroll
    for (int ct = 0; ct < 4; ++ct) {
      bf16x8 bk = *(const bf16x8*)&Ks[(ct * 16 + il) * 72 + ks * 32 + q * 8];
      sacc[ct] = __builtin_amdgcn_mfma_f32_16x16x32_bf16(aq, bk, sacc[ct], 0, 0, 0);
    }
  }

  // row softmax: row = 16w+4q+r; its 64 cols live in this quad (16 il x 4 tiles)
#pragma unroll
  for (int r = 0; r < 4; ++r) {
    float s0 = sacc[0][r] * 0.125f, s1 = sacc[1][r] * 0.125f,
          s2 = sacc[2][r] * 0.125f, s3 = sacc[3][r] * 0.125f;
    float mx = fmaxf(fmaxf(s0, s1), fmaxf(s2, s3));
#pragma unroll
    for (int o = 1; o < 16; o <<= 1) mx = fmaxf(mx, __shfl_xor(mx, o, 64));
    float e0 = __expf(s0 - mx), e1 = __expf(s1 - mx),
          e2 = __expf(s2 - mx), e3 = __expf(s3 - mx);
    float sum = e0 + e1 + e2 + e3;
#pragma unroll
    for (int o = 1; o < 16; o <<= 1) sum += __shfl_xor(sum, o, 64);
    float inv = 1.0f / sum;
    int prow = w * 16 + q * 4 + r;
    Ps[prow * 72 + 0 * 16 + il] = f2bf(e0 * inv);
    Ps[prow * 72 + 1 * 16 + il] = f2bf(e1 * inv);
    Ps[prow * 72 + 2 * 16 + il] = f2bf(e2 * inv);
    Ps[prow * 72 + 3 * 16 + il] = f2bf(e3 * inv);
  }
  __syncthreads();

  // O = P V : A-frag from Ps rows, B-frag from Vt rows (= V columns)
  f32x4 oacc[4] = {};
#pragma unroll
  for (int ks = 0; ks < 2; ++ks) {
    bf16x8 ap = *(const bf16x8*)&Ps[(w * 16 + il) * 72 + ks * 32 + q * 8];
#pragma unroll
    for (int dt = 0; dt < 4; ++dt) {
      bf16x8 bv = *(const bf16x8*)&Vt[(dt * 16 + il) * 72 + ks * 32 + q * 8];
      oacc[dt] = __builtin_amdgcn_mfma_f32_16x16x32_bf16(ap, bv, oacc[dt], 0, 0, 0);
    }
  }

  const float* cs = cso + ((long)b * NW_ + n) * D_ + h * 64;
#pragma unroll
  for (int dt = 0; dt < 4; ++dt) {
    int col = dt * 16 + il;
    float cadd = 0.25f * cs[col];
#pragma unroll
    for (int r = 0; r < 4; ++r) {
      int row = w * 16 + q * 4 + r;
      qkv[(rowbase + row) * 3072 + h * 64 + col] = f2bf(oacc[dt][r] + cadd);
    }
  }
}

extern "C" void kernel_launch(void* const* d_in, const int* in_sizes, int n_in,
                              void* d_out, int out_size, void* d_ws, size_t ws_size,
                              hipStream_t stream)
{
  (void)in_sizes; (void)n_in; (void)out_size; (void)ws_size;
  const float* x      = (const float*)d_in[0];
  const float* Wqkv   = (const float*)d_in[1];
  const float* Wout   = (const float*)d_in[2];
  const float* bout   = (const float*)d_in[3];
  const float* Wcross = (const float*)d_in[4];
  const float* bcross = (const float*)d_in[5];
  const int*   jitter = (const int*)d_in[6];
  float* out = (float*)d_out;

  // ws layout (bytes), total 144,769,024 (same footprint as passing round 3):
  char* ws = (char*)d_ws;
  u16*   qkv    = (u16*)ws;                        // 100,663,296 (y bf16 aliases @0)
  u16*   y      = (u16*)ws;
  u16*   xb     = (u16*)(ws + 100663296);          // 33,554,432
  u16*   wqkvb  = (u16*)(ws + 134217728);          //  6,291,456
  u16*   wtmp   = (u16*)(ws + 140509184);          //  2,097,152 (Wcross, then Wout)
  float* scores = (float*)(ws + 142606336);        //     65,536
  float* summ   = (float*)(ws + 142671872);        //  1,048,576
  float* cso    = (float*)(ws + 143720448);        //  1,048,576

  dim3 blk(256);
  dim3 gblk(512);
  // fused input casts: x->xb, Wqkv->wqkvb, Wcross->wtmp
  cvt3_k<<<20480, blk, 0, stream>>>(x, xb, Wqkv, wqkvb, Wcross, wtmp);
  // cross-score path (grid 4x64 = 256 blocks, %8==0)
  gemm256<<<dim3(4, 64), gblk, 0, stream>>>(xb, wtmp, y, nullptr, bcross, 16384, 1024, 1024, 1024);
  cvt_k<<<1024, blk, 0, stream>>>(Wout, wtmp, 1048576L);   // wtmp free after cross gemm
  scores_k<<<4096, blk, 0, stream>>>(y, scores);
  summar_k<<<256, blk, 0, stream>>>(x, scores, summ);
  cross_k<<<256, blk, 0, stream>>>(summ, jitter, cso);
  // main path (y dead now; qkv overwrites it) (grid 12x64 = 768 blocks, %8==0)
  gemm256<<<dim3(12, 64), gblk, 0, stream>>>(xb, wqkvb, qkv, nullptr, nullptr, 16384, 3072, 1024, 1024);
  attn_win<<<4096, blk, 0, stream>>>(qkv, cso);            // in-place -> q-slice
  gemm256<<<dim3(4, 64), gblk, 0, stream>>>(qkv, wtmp, nullptr, out, bout, 16384, 1024, 1024, 3072);
}

// Round 5
// 394.187 us; speedup vs baseline: 1.0426x; 1.0426x over previous
//
#include <hip/hip_runtime.h>

typedef unsigned short u16;
typedef float f32x4 __attribute__((ext_vector_type(4)));
typedef __bf16 bf16x8 __attribute__((ext_vector_type(8)));

#define T_ 4096
#define D_ 1024
#define NW_ 64

__device__ __forceinline__ float b2f(u16 u) {
  return __uint_as_float(((unsigned)u) << 16);
}
__device__ __forceinline__ u16 f2bf(float f) {
  unsigned u = __float_as_uint(f);
  u += 0x7fffu + ((u >> 16) & 1u);   // RNE
  return (u16)(u >> 16);
}
__device__ __forceinline__ void g2l16(const u16* g, u16* l) {
  __builtin_amdgcn_global_load_lds((const __attribute__((address_space(1))) void*)g,
                                   (__attribute__((address_space(3))) void*)l, 16, 0, 0);
}

// fused fp32->bf16 casts: x (16384 blk), Wqkv (3072 blk), Wcross (1024 blk)
__global__ __launch_bounds__(256) void cvt3_k(const float* __restrict__ s0, u16* __restrict__ d0,
                                              const float* __restrict__ s1, u16* __restrict__ d1,
                                              const float* __restrict__ s2, u16* __restrict__ d2)
{
  long bid = blockIdx.x;
  const float* src; u16* dst; long base;
  if (bid < 16384)      { src = s0; dst = d0; base = bid * 1024; }
  else if (bid < 19456) { src = s1; dst = d1; base = (bid - 16384) * 1024; }
  else                  { src = s2; dst = d2; base = (bid - 19456) * 1024; }
  long i = base + (long)threadIdx.x * 4;
  float4 v = *(const float4*)(src + i);
  ushort4 o;
  o.x = f2bf(v.x); o.y = f2bf(v.y); o.z = f2bf(v.z); o.w = f2bf(v.w);
  *(ushort4*)(dst + i) = o;
}

__global__ __launch_bounds__(256) void cvt_k(const float* __restrict__ src,
                                             u16* __restrict__ dst, long n)
{
  long i = ((long)blockIdx.x * 256 + threadIdx.x) * 4;
  if (i >= n) return;
  float4 v = *(const float4*)(src + i);
  ushort4 o;
  o.x = f2bf(v.x); o.y = f2bf(v.y); o.z = f2bf(v.z); o.w = f2bf(v.w);
  *(ushort4*)(dst + i) = o;
}

// C(M,N) = A(M,K;lda) @ B(N,K)^T [+ bias], A/B bf16, fp32 accum.
// 256x256 tile, BK=64, 512 thr (8 waves, 2x4). m201-faithful 8-phase schedule
// (round-2 verified): reads; stage; barrier; lgkmcnt(0); setprio MFMA; barrier;
// counted vmcnt(6) ONLY at phases 4 and 8 (FIFO ledger verified). T2 LDS
// swizzle (linear gload_lds dest + inverse-swizzled global src), bijective XCD
// blockIdx swizzle, LDS-staged coalesced epilogue.
// NEW: if scores4 != nullptr, column-blocks with n0 >= N skip the C write and
// instead tanh-row-reduce their tile into scores4[row*4 + (n0-N)/256]
// (fused cross-score path; bias_y added pre-tanh). B may have more than N rows.
// Requires M % 256 == 0, grid-N % 256 == 0, K % 128 == 0.
__global__ __launch_bounds__(512, 2) void gemm256(
    const u16* __restrict__ A, const u16* __restrict__ Bm,
    u16* __restrict__ C16, float* __restrict__ C32,
    const float* __restrict__ bias, int M, int N, int K, int lda,
    float* __restrict__ scores4, const float* __restrict__ bias_y)
{
  // one 128KB region: A stripes at [0,32K) u16, B stripes at [32K,64K) u16.
  // A stripe (buf,mh): rows rho=0..127 <-> global m0 + mh*64 + (rho&63) + (rho>>6)*128
  // B stripe (buf,nh): rows rho=0..127 <-> global n0 + nh*32 + (rho&31) + (rho>>5)*64
  // 16B slot s of row rho holds k-group (s ^ (rho&7))  [XOR swizzle, involution]
  __shared__ u16 SH[65536];
  (void)M;
  const int tid = threadIdx.x;
  const int lane = tid & 63;
  const int w = tid >> 6;
  const int wm = w >> 2, wn = w & 3;
  const int q = lane >> 4, il = lane & 15;

  // XCD-aware bijective chunked swizzle (nwg % 8 == 0 for all our grids)
  const int nbx = gridDim.x;
  const int nwg = nbx * (int)gridDim.y;
  const int bid = (int)blockIdx.y * nbx + (int)blockIdx.x;
  const int nid = (bid & 7) * (nwg >> 3) + (bid >> 3);
  const long m0 = (long)(nid / nbx) * 256;
  const long n0 = (long)(nid % nbx) * 256;

  const int nt = K >> 6;               // # K-tiles, even (K % 128 == 0)
  const int ntm1 = nt - 1;

  // staging constants: 2 load-units per stripe per thread (u = i*512 + tid)
  const int u0 = tid, u1 = 512 + tid;
  const int r0 = u0 >> 3, r1 = u1 >> 3;
  const int sx0 = ((u0 & 7) ^ (r0 & 7)) << 3;   // pre-swizzled source k-offset (elems)
  const int sx1 = ((u1 & 7) ^ (r1 & 7)) << 3;
  const long gar0 = m0 + (r0 >> 6) * 128 + (r0 & 63);
  const long gar1 = m0 + (r1 >> 6) * 128 + (r1 & 63);
  const long gbr0 = n0 + (r0 >> 5) * 64 + (r0 & 31);
  const long gbr1 = n0 + (r1 >> 5) * 64 + (r1 & 31);
  const int dl = w * 512;              // wave-uniform LDS dest (u16), HW adds lane*16B

  // fragment read constants (swizzled k-slot = slot ^ (row&7))
  const int aro = (wm * 64 + il) * 64;
  const int bro = (wn * 32 + il) * 64;
  const int ax = (il & 7) << 3;
  const int ko0 = (q * 8) ^ ax;        // kk=0
  const int ko1 = (32 + q * 8) ^ ax;   // kk=1

  f32x4 acc[8][4] = {};
  bf16x8 af[4], bf0[2][2], bf1[2][2];

#define ASP(BUF, MH) (&SH[((BUF) * 2 + (MH)) * 8192])
#define BSP(BUF, NH) (&SH[32768 + ((BUF) * 2 + (NH)) * 8192])
#define STGA(BUF, MH, KT) do { \
    g2l16(A + (gar0 + (MH) * 64) * (long)lda + (KT) * 64 + sx0, ASP(BUF, MH) + dl); \
    g2l16(A + (gar1 + (MH) * 64) * (long)lda + (KT) * 64 + sx1, ASP(BUF, MH) + 4096 + dl); \
  } while (0)
#define STGB(BUF, NH, KT) do { \
    g2l16(Bm + (gbr0 + (NH) * 32) * (long)K + (KT) * 64 + sx0, BSP(BUF, NH) + dl); \
    g2l16(Bm + (gbr1 + (NH) * 32) * (long)K + (KT) * 64 + sx1, BSP(BUF, NH) + 4096 + dl); \
  } while (0)
#define LDAF(BUF, MH) do { \
    _Pragma("unroll") for (int f = 0; f < 4; ++f) { \
      af[f] = *(const bf16x8*)(ASP(BUF, MH) + aro + f * 1024 + ko0); \
      afk[f] = *(const bf16x8*)(ASP(BUF, MH) + aro + f * 1024 + ko1); \
    } } while (0)
#define LDBF(BUF, NH, BF) do { \
    _Pragma("unroll") for (int j = 0; j < 2; ++j) { \
      BF[j][0] = *(const bf16x8*)(BSP(BUF, NH) + bro + j * 1024 + ko0); \
      BF[j][1] = *(const bf16x8*)(BSP(BUF, NH) + bro + j * 1024 + ko1); \
    } } while (0)
#define MFMAQ(MH, NH, BF) do { \
    _Pragma("unroll") for (int f = 0; f < 4; ++f) { \
      _Pragma("unroll") for (int j = 0; j < 2; ++j) { \
        acc[(MH)*4+f][(NH)*2+j] = __builtin_amdgcn_mfma_f32_16x16x32_bf16(af[f], BF[j][0], acc[(MH)*4+f][(NH)*2+j], 0, 0, 0); \
        acc[(MH)*4+f][(NH)*2+j] = __builtin_amdgcn_mfma_f32_16x16x32_bf16(afk[f], BF[j][1], acc[(MH)*4+f][(NH)*2+j], 0, 0, 0); \
      } } } while (0)
#define BARR() __builtin_amdgcn_s_barrier()
#define WL0() asm volatile("s_waitcnt lgkmcnt(0)" ::: "memory")
#define WV6() asm volatile("s_waitcnt vmcnt(6)" ::: "memory")
#define PRIO(x) __builtin_amdgcn_s_setprio(x)

  bf16x8 afk[4];

  // prologue: tile0 all 4 half-tiles + tile1 {A0,B0,B1}; vmcnt(6) completes
  // exactly tile0's 8 loads (FIFO), leaving 6 outstanding entering P1.
  STGA(0, 0, 0); STGB(0, 0, 0); STGB(0, 1, 0); STGA(0, 1, 0);
  STGA(1, 0, 1); STGB(1, 0, 1); STGB(1, 1, 1);
  WV6();
  BARR();

  // Steady state FIFO (2 loads/phase): entering P1: 6 outstanding; P4/P8
  // vmcnt(6) completes the 8 oldest = the 4 half-tiles consumed in the next
  // 4 phases. Every stage targets a region whose last read was the previous
  // phase (reads(p) all complete before any wave passes p's closing barrier).
  for (int tt = 0; tt < nt; tt += 2) {
    const int t1 = tt + 1;
    const int t2 = tt + 2 <= ntm1 ? tt + 2 : ntm1;  // tail: valid addr, dead data
    const int t3 = tt + 3 <= ntm1 ? tt + 3 : ntm1;
    // P1: reads A0,B0(buf0); stage A1(buf1,t1)  [A1 buf1 last read P7 prev iter]
    LDAF(0, 0); LDBF(0, 0, bf0);
    STGA(1, 1, t1);
    BARR(); WL0();
    PRIO(1); MFMAQ(0, 0, bf0); PRIO(0);
    BARR();
    // P2: reads B1(buf0); stage A0(buf0,t2)  [last read P1]
    LDBF(0, 1, bf1);
    STGA(0, 0, t2);
    BARR(); WL0();
    PRIO(1); MFMAQ(0, 1, bf1); PRIO(0);
    BARR();
    // P3: reads A1(buf0); stage B0(buf0,t2)  [last read P1]
    LDAF(0, 1);
    STGB(0, 0, t2);
    BARR(); WL0();
    PRIO(1); MFMAQ(1, 0, bf0); PRIO(0);
    BARR();
    // P4: regs only; stage B1(buf0,t2)  [last read P2]; counted wait
    STGB(0, 1, t2);
    BARR();
    PRIO(1); MFMAQ(1, 1, bf1); PRIO(0);
    WV6(); BARR();
    // P5: reads A0,B0(buf1); stage A1(buf0,t2)  [last read P3]
    LDAF(1, 0); LDBF(1, 0, bf0);
    STGA(0, 1, t2);
    BARR(); WL0();
    PRIO(1); MFMAQ(0, 0, bf0); PRIO(0);
    BARR();
    // P6: reads B1(buf1); stage A0(buf1,t3)  [last read P5]
    LDBF(1, 1, bf1);
    STGA(1, 0, t3);
    BARR(); WL0();
    PRIO(1); MFMAQ(0, 1, bf1); PRIO(0);
    BARR();
    // P7: reads A1(buf1); stage B0(buf1,t3)  [last read P5]
    LDAF(1, 1);
    STGB(1, 0, t3);
    BARR(); WL0();
    PRIO(1); MFMAQ(1, 0, bf0); PRIO(0);
    BARR();
    // P8: regs only; stage B1(buf1,t3)  [last read P6]; counted wait
    STGB(1, 1, t3);
    BARR();
    PRIO(1); MFMAQ(1, 1, bf1); PRIO(0);
    WV6(); BARR();
  }

  asm volatile("s_waitcnt vmcnt(0)" ::: "memory");  // drain tail stages (they DMA into SH)
  __syncthreads();

  // ---- fused cross-score path: tanh row-reduce, no C write ----
  if (scores4 && n0 >= N) {
    float* part = (float*)SH;            // [256][4] fp32 partials
    const int sub = (int)((n0 - N) >> 8);
    float bv[4];
#pragma unroll
    for (int ni = 0; ni < 4; ++ni)
      bv[ni] = bias_y ? bias_y[(n0 - N) + wn * 64 + ni * 16 + il] : 0.0f;
#pragma unroll
    for (int mi = 0; mi < 8; ++mi) {
#pragma unroll
      for (int r = 0; r < 4; ++r) {
        float s = tanhf(acc[mi][0][r] + bv[0]) + tanhf(acc[mi][1][r] + bv[1])
                + tanhf(acc[mi][2][r] + bv[2]) + tanhf(acc[mi][3][r] + bv[3]);
#pragma unroll
        for (int o = 1; o < 16; o <<= 1) s += __shfl_xor(s, o, 64);
        if (il == 0) {
          const int rowl = wm * 128 + (mi >> 2) * 64 + (mi & 3) * 16 + q * 4 + r;
          part[rowl * 4 + wn] = s;
        }
      }
    }
    __syncthreads();
    if (tid < 256) {
      float t = part[tid * 4] + part[tid * 4 + 1] + part[tid * 4 + 2] + part[tid * 4 + 3];
      scores4[(m0 + tid) * 4 + sub] = t;
    }
    return;
  }

  // ---- epilogue: stage C tile in LDS, emit full-line coalesced stores ----
  if (C32) {
    // fp32: two 128-row halves (128*256*4B = 128KB each). wm==h waves own half h.
    float* Cf = (float*)SH;
#pragma unroll
    for (int h = 0; h < 2; ++h) {
      if (wm == h) {
#pragma unroll
        for (int ni = 0; ni < 4; ++ni) {
          const int ccol = wn * 64 + ni * 16 + il;
          const float bv = bias ? bias[n0 + ccol] : 0.0f;
#pragma unroll
          for (int mi = 0; mi < 8; ++mi) {
#pragma unroll
            for (int r = 0; r < 4; ++r) {
              const int crow = (mi >> 2) * 64 + (mi & 3) * 16 + q * 4 + r;
              const int byte = (crow * 1024 + ccol * 4) ^ (((crow >> 2) & 1) << 6);
              *(float*)((char*)Cf + byte) = acc[mi][ni][r] + bv;
            }
          }
        }
      }
      __syncthreads();
#pragma unroll
      for (int i = 0; i < 16; ++i) {
        const int u = i * 512 + tid;
        const int crow = u >> 6, c16 = u & 63;
        const int byte = (crow * 1024 + c16 * 16) ^ (((crow >> 2) & 1) << 6);
        float4 v = *(const float4*)((char*)Cf + byte);
        *(float4*)(C32 + (m0 + h * 128 + crow) * N + n0 + c16 * 4) = v;
      }
      __syncthreads();
    }
  } else {
    // bf16: whole 256x256 tile = 128KB.
    u16* Cs = (u16*)SH;
#pragma unroll
    for (int ni = 0; ni < 4; ++ni) {
      const int ccol = wn * 64 + ni * 16 + il;
      const float bv = bias ? bias[n0 + ccol] : 0.0f;
#pragma unroll
      for (int mi = 0; mi < 8; ++mi) {
#pragma unroll
        for (int r = 0; r < 4; ++r) {
          const int crow = wm * 128 + (mi >> 2) * 64 + (mi & 3) * 16 + q * 4 + r;
          const int byte = (crow * 512 + ccol * 2) ^ (((crow >> 2) & 3) << 5);
          *(u16*)((char*)Cs + byte) = f2bf(acc[mi][ni][r] + bv);
        }
      }
    }
    __syncthreads();
#pragma unroll
    for (int i = 0; i < 16; ++i) {
      const int u = i * 512 + tid;
      const int crow = u >> 5, c16 = u & 31;
      const int byte = (crow * 512 + c16 * 16) ^ (((crow >> 2) & 3) << 5);
      uint4 v = *(const uint4*)((char*)Cs + byte);
      *(uint4*)(C16 + (m0 + crow) * N + n0 + c16 * 8) = v;
    }
  }
#undef ASP
#undef BSP
#undef STGA
#undef STGB
#undef LDAF
#undef LDBF
#undef MFMAQ
#undef BARR
#undef WL0
#undef WV6
#undef PRIO
}

// per-window softmax over scores -> weighted sum of fp32 x rows -> summaries
// scores4[row*4 + 0..3] holds partial tanh sums (pre 1/1024 scaling).
__global__ __launch_bounds__(256) void summar_k(const float* __restrict__ x,
                                                const float* __restrict__ s4,
                                                float* __restrict__ summ)
{
  __shared__ float wts[64];
  const int tid = threadIdx.x;
  const int b = blockIdx.x >> 6, n = blockIdx.x & 63;
  if (tid < 64) {
    const long r4 = ((long)b * T_ + n * 64 + tid) * 4;
    float v = (s4[r4] + s4[r4 + 1] + s4[r4 + 2] + s4[r4 + 3]) * (1.0f / 1024.0f);
    float mx = v;
#pragma unroll
    for (int o = 32; o; o >>= 1) mx = fmaxf(mx, __shfl_xor(mx, o, 64));
    float e = __expf(v - mx);
    float s = e;
#pragma unroll
    for (int o = 32; o; o >>= 1) s += __shfl_xor(s, o, 64);
    wts[tid] = e / s;
  }
  __syncthreads();
  const int d0 = tid * 4;
  const float* xp = x + ((long)b * T_ + n * 64) * D_ + d0;
  float a0 = 0, a1 = 0, a2 = 0, a3 = 0;
#pragma unroll 4
  for (int wd = 0; wd < 64; ++wd) {
    float4 v = *(const float4*)(xp + (long)wd * D_);
    float wv = wts[wd];
    a0 += wv * v.x; a1 += wv * v.y; a2 += wv * v.z; a3 += wv * v.w;
  }
  *(float4*)(summ + ((long)b * NW_ + n) * D_ + d0) = make_float4(a0, a1, a2, a3);
}

// cross-summary attention: cs_out[b,n,:] = softmax(summ[n]·jit[m]/32)_m @ jit
__global__ __launch_bounds__(256) void cross_k(const float* __restrict__ summ,
                                               const int* __restrict__ jitter,
                                               float* __restrict__ cso)
{
  __shared__ float sm[64], pm[64];
  __shared__ int jidx[64];
  const int tid = threadIdx.x;
  const int b = blockIdx.x >> 6, n = blockIdx.x & 63;
  if (tid < 64) jidx[tid] = jitter[tid];
  __syncthreads();
  const int m = tid >> 2, part = tid & 3;
  const float* sn = summ + ((long)b * NW_ + n) * D_;
  const float* sj = summ + ((long)b * NW_ + jidx[m]) * D_;
  float p = 0.f;
  for (int d = part * 256; d < part * 256 + 256; d += 4) {
    float4 aa = *(const float4*)(sn + d);
    float4 bb = *(const float4*)(sj + d);
    p += aa.x * bb.x + aa.y * bb.y + aa.z * bb.z + aa.w * bb.w;
  }
  p += __shfl_xor(p, 1, 64);
  p += __shfl_xor(p, 2, 64);
  if (part == 0) sm[m] = p * (1.0f / 32.0f);
  __syncthreads();
  if (tid < 64) {
    float v = sm[tid], mx = v;
#pragma unroll
    for (int o = 32; o; o >>= 1) mx = fmaxf(mx, __shfl_xor(mx, o, 64));
    float e = __expf(v - mx), s = e;
#pragma unroll
    for (int o = 32; o; o >>= 1) s += __shfl_xor(s, o, 64);
    pm[tid] = e / s;
  }
  __syncthreads();
  const int d0 = tid * 4;
  float a0 = 0, a1 = 0, a2 = 0, a3 = 0;
  for (int mm = 0; mm < 64; ++mm) {
    const float* sr = summ + ((long)b * NW_ + jidx[mm]) * D_ + d0;
    float wv = pm[mm];
    float4 vv = *(const float4*)sr;
    a0 += wv * vv.x; a1 += wv * vv.y; a2 += wv * vv.z; a3 += wv * vv.w;
  }
  *(float4*)(cso + ((long)b * NW_ + n) * D_ + d0) = make_float4(a0, a1, a2, a3);
}

// windowed attention, one block per (b,h,n); writes final = local + 0.25*cs
// IN-PLACE into the q-slice of qkv (each block writes only the region it reads).
__global__ __launch_bounds__(256) void attn_win(u16* qkv,
                                                const float* __restrict__ cso)
{
  __shared__ u16 Qs[64 * 72], Ks[64 * 72], Vt[64 * 72], Ps[64 * 72];
  unsigned* Vt32 = (unsigned*)Vt;          // word stride 36/row (byte 144, b128-aligned)
  const int tid = threadIdx.x;
  const int lane = tid & 63;
  const int w = tid >> 6;
  const int q = lane >> 4, il = lane & 15;
  const int bid = blockIdx.x;
  const int n = bid & 63;
  const int h = (bid >> 6) & 15;
  const int b = bid >> 10;
  const long rowbase = (long)b * T_ + n * 64;

#pragma unroll
  for (int i = 0; i < 2; ++i) {
    int u = i * 256 + tid;
    int row = u >> 3, cp = u & 7;
    const u16* src = qkv + (rowbase + row) * 3072 + h * 64 + cp * 8;
    uint4 qv = *(const uint4*)src;
    uint4 kv = *(const uint4*)(src + 1024);
    uint4 vv = *(const uint4*)(src + 2048);
    *(uint4*)&Qs[row * 72 + cp * 8] = qv;
    *(uint4*)&Ks[row * 72 + cp * 8] = kv;
    // V transpose via row-pair packing: tid/tid^8 hold rows 2p,2p+1 (same cols).
    union { uint4 v; unsigned u[4]; } mine, part;
    mine.v = vv;
#pragma unroll
    for (int m = 0; m < 4; ++m) part.u[m] = __shfl_xor(mine.u[m], 8, 64);
    const bool even = ((row & 1) == 0);
    const int p = row >> 1;
#pragma unroll
    for (int m = 0; m < 4; ++m) {
      unsigned word = even ? ((mine.u[m] & 0xffffu) | (part.u[m] << 16))
                           : ((part.u[m] >> 16)     | (mine.u[m] & 0xffff0000u));
      int c = cp * 8 + 2 * m + (even ? 0 : 1);     // Vt row = V column
      Vt32[c * 36 + p] = word;                     // u32 store: 4 stores vs 8, ~8-way
    }
  }
  __syncthreads();

  // S = Q K^T : wave w owns rows [16w,16w+16), 4 col-tiles of 16
  f32x4 sacc[4] = {};
#pragma unroll
  for (int ks = 0; ks < 2; ++ks) {
    bf16x8 aq = *(const bf16x8*)&Qs[(w * 16 + il) * 72 + ks * 32 + q * 8];
#pragma unroll
    for (int ct = 0; ct < 4; ++ct) {
      bf16x8 bk = *(const bf16x8*)&Ks[(ct * 16 + il) * 72 + ks * 32 + q * 8];
      sacc[ct] = __builtin_amdgcn_mfma_f32_16x16x32_bf16(aq, bk, sacc[ct], 0, 0, 0);
    }
  }

  // row softmax: row = 16w+4q+r; its 64 cols live in this quad (16 il x 4 tiles)
#pragma unroll
  for (int r = 0; r < 4; ++r) {
    float s0 = sacc[0][r] * 0.125f, s1 = sacc[1][r] * 0.125f,
          s2 = sacc[2][r] * 0.125f, s3 = sacc[3][r] * 0.125f;
    float mx = fmaxf(fmaxf(s0, s1), fmaxf(s2, s3));
#pragma unroll
    for (int o = 1; o < 16; o <<= 1) mx = fmaxf(mx, __shfl_xor(mx, o, 64));
    float e0 = __expf(s0 - mx), e1 = __expf(s1 - mx),
          e2 = __expf(s2 - mx), e3 = __expf(s3 - mx);
    float sum = e0 + e1 + e2 + e3;
#pragma unroll
    for (int o = 1; o < 16; o <<= 1) sum += __shfl_xor(sum, o, 64);
    float inv = 1.0f / sum;
    int prow = w * 16 + q * 4 + r;
    Ps[prow * 72 + 0 * 16 + il] = f2bf(e0 * inv);
    Ps[prow * 72 + 1 * 16 + il] = f2bf(e1 * inv);
    Ps[prow * 72 + 2 * 16 + il] = f2bf(e2 * inv);
    Ps[prow * 72 + 3 * 16 + il] = f2bf(e3 * inv);
  }
  __syncthreads();

  // O = P V : A-frag from Ps rows, B-frag from Vt rows (= V columns)
  f32x4 oacc[4] = {};
#pragma unroll
  for (int ks = 0; ks < 2; ++ks) {
    bf16x8 ap = *(const bf16x8*)&Ps[(w * 16 + il) * 72 + ks * 32 + q * 8];
#pragma unroll
    for (int dt = 0; dt < 4; ++dt) {
      bf16x8 bv = *(const bf16x8*)&Vt[(dt * 16 + il) * 72 + ks * 32 + q * 8];
      oacc[dt] = __builtin_amdgcn_mfma_f32_16x16x32_bf16(ap, bv, oacc[dt], 0, 0, 0);
    }
  }

  const float* cs = cso + ((long)b * NW_ + n) * D_ + h * 64;
#pragma unroll
  for (int dt = 0; dt < 4; ++dt) {
    int col = dt * 16 + il;
    float cadd = 0.25f * cs[col];
#pragma unroll
    for (int r = 0; r < 4; ++r) {
      int row = w * 16 + q * 4 + r;
      qkv[(rowbase + row) * 3072 + h * 64 + col] = f2bf(oacc[dt][r] + cadd);
    }
  }
}

extern "C" void kernel_launch(void* const* d_in, const int* in_sizes, int n_in,
                              void* d_out, int out_size, void* d_ws, size_t ws_size,
                              hipStream_t stream)
{
  (void)in_sizes; (void)n_in; (void)out_size; (void)ws_size;
  const float* x      = (const float*)d_in[0];
  const float* Wqkv   = (const float*)d_in[1];
  const float* Wout   = (const float*)d_in[2];
  const float* bout   = (const float*)d_in[3];
  const float* Wcross = (const float*)d_in[4];
  const float* bcross = (const float*)d_in[5];
  const int*   jitter = (const int*)d_in[6];
  float* out = (float*)d_out;

  // ws layout (bytes), total <= 144,769,024 (prior passing footprint):
  char* ws = (char*)d_ws;
  u16*   qkv     = (u16*)ws;                       // 100,663,296
  u16*   xb      = (u16*)(ws + 100663296);         // 33,554,432
  u16*   wqkvb   = (u16*)(ws + 134217728);         //  6,291,456 (rows 0..3071 of B)
  u16*   wtmp    = (u16*)(ws + 140509184);         //  2,097,152 (Wcross rows 3072..4095, then Wout)
  float* scores4 = (float*)(ws + 142606336);       //    262,144 (16384 rows x 4 partials)
  float* summ    = (float*)(ws + 142868480);       //  1,048,576 (ends 143,917,056)
  float* cso     = (float*)d_out;                  //  1,048,576 (d_out scratch; overwritten by final gemm)

  dim3 blk(256);
  dim3 gblk(512);
  // fused input casts: x->xb, Wqkv->wqkvb, Wcross->wtmp (contiguous with wqkvb)
  cvt3_k<<<20480, blk, 0, stream>>>(x, xb, Wqkv, wqkvb, Wcross, wtmp);
  // combined QKV + cross-score gemm: B has 4096 rows ([Wqkv; Wcross]); cols
  // 0..3071 -> qkv (C16, stride N=3072); cols 3072..4095 -> tanh-reduced into
  // scores4 (no C write). grid 16x64 = 1024 blocks, %8==0.
  gemm256<<<dim3(16, 64), gblk, 0, stream>>>(xb, wqkvb, qkv, nullptr, nullptr,
                                             16384, 3072, 1024, 1024, scores4, bcross);
  cvt_k<<<1024, blk, 0, stream>>>(Wout, wtmp, 1048576L);   // wtmp free after combined gemm
  summar_k<<<256, blk, 0, stream>>>(x, scores4, summ);
  cross_k<<<256, blk, 0, stream>>>(summ, jitter, cso);
  attn_win<<<4096, blk, 0, stream>>>(qkv, cso);            // in-place -> q-slice
  gemm256<<<dim3(4, 64), gblk, 0, stream>>>(qkv, wtmp, nullptr, out, bout,
                                            16384, 1024, 1024, 3072, nullptr, nullptr);
}

// Round 6
// 371.083 us; speedup vs baseline: 1.1075x; 1.0623x over previous
//
#include <hip/hip_runtime.h>

typedef unsigned short u16;
typedef float f32x4 __attribute__((ext_vector_type(4)));
typedef __bf16 bf16x8 __attribute__((ext_vector_type(8)));

#define T_ 4096
#define D_ 1024
#define NW_ 64

__device__ __forceinline__ float b2f(u16 u) {
  return __uint_as_float(((unsigned)u) << 16);
}
__device__ __forceinline__ u16 f2bf(float f) {
  unsigned u = __float_as_uint(f);
  u += 0x7fffu + ((u >> 16) & 1u);   // RNE
  return (u16)(u >> 16);
}
__device__ __forceinline__ void g2l16(const u16* g, u16* l) {
  __builtin_amdgcn_global_load_lds((const __attribute__((address_space(1))) void*)g,
                                   (__attribute__((address_space(3))) void*)l, 16, 0, 0);
}

// fused fp32->bf16 casts: x (16384 blk), Wqkv (3072 blk), Wcross (1024 blk)
__global__ __launch_bounds__(256) void cvt3_k(const float* __restrict__ s0, u16* __restrict__ d0,
                                              const float* __restrict__ s1, u16* __restrict__ d1,
                                              const float* __restrict__ s2, u16* __restrict__ d2)
{
  long bid = blockIdx.x;
  const float* src; u16* dst; long base;
  if (bid < 16384)      { src = s0; dst = d0; base = bid * 1024; }
  else if (bid < 19456) { src = s1; dst = d1; base = (bid - 16384) * 1024; }
  else                  { src = s2; dst = d2; base = (bid - 19456) * 1024; }
  long i = base + (long)threadIdx.x * 4;
  float4 v = *(const float4*)(src + i);
  ushort4 o;
  o.x = f2bf(v.x); o.y = f2bf(v.y); o.z = f2bf(v.z); o.w = f2bf(v.w);
  *(ushort4*)(dst + i) = o;
}

__global__ __launch_bounds__(256) void cvt_k(const float* __restrict__ src,
                                             u16* __restrict__ dst, long n)
{
  long i = ((long)blockIdx.x * 256 + threadIdx.x) * 4;
  if (i >= n) return;
  float4 v = *(const float4*)(src + i);
  ushort4 o;
  o.x = f2bf(v.x); o.y = f2bf(v.y); o.z = f2bf(v.z); o.w = f2bf(v.w);
  *(ushort4*)(dst + i) = o;
}

// C(M,N) = A(M,K;lda) @ B(N,K)^T [+ bias], A/B bf16, fp32 accum.
// 256x256 tile, BK=64, 512 thr (8 waves, 2x4). 8-phase schedule, round-2
// sync structure (stages + vmcnt(6) at P4/P8 only, FIFO ledger verified).
// CHANGE vs round 2: no lgkmcnt(0) BEFORE the MFMA cluster — reads are
// ordered (B-frags then A-frags) so the compiler emits progressive counted
// lgkmcnt per dependency, overlapping the read burst's tail under the first
// MFMAs. Cross-wave invariant "reads(p) done before closing barrier" is
// restored by sched_barrier(0)+lgkmcnt(0) AFTER the cluster (free: already
// drained; walls ds_reads from sinking past the barrier into stage(p+1)'s
// overwrite window). T2 LDS swizzle, setprio, XCD swizzle, LDS-staged
// coalesced epilogue. Requires M,N % 256 == 0, K % 128 == 0.
__global__ __launch_bounds__(512, 2) void gemm256(
    const u16* __restrict__ A, const u16* __restrict__ Bm,
    u16* __restrict__ C16, float* __restrict__ C32,
    const float* __restrict__ bias, int M, int N, int K, int lda)
{
  // one 128KB region: A stripes at [0,32K) u16, B stripes at [32K,64K) u16.
  // A stripe (buf,mh): rows rho=0..127 <-> global m0 + mh*64 + (rho&63) + (rho>>6)*128
  // B stripe (buf,nh): rows rho=0..127 <-> global n0 + nh*32 + (rho&31) + (rho>>5)*64
  // 16B slot s of row rho holds k-group (s ^ (rho&7))  [XOR swizzle, involution]
  __shared__ u16 SH[65536];
  (void)M;
  const int tid = threadIdx.x;
  const int lane = tid & 63;
  const int w = tid >> 6;
  const int wm = w >> 2, wn = w & 3;
  const int q = lane >> 4, il = lane & 15;

  // XCD-aware bijective chunked swizzle (nwg % 8 == 0 for all our grids)
  const int nbx = gridDim.x;
  const int nwg = nbx * (int)gridDim.y;
  const int bid = (int)blockIdx.y * nbx + (int)blockIdx.x;
  const int nid = (bid & 7) * (nwg >> 3) + (bid >> 3);
  const long m0 = (long)(nid / nbx) * 256;
  const long n0 = (long)(nid % nbx) * 256;

  const int nt = K >> 6;               // # K-tiles, even (K % 128 == 0)
  const int ntm1 = nt - 1;

  // staging constants: 2 load-units per stripe per thread (u = i*512 + tid)
  const int u0 = tid, u1 = 512 + tid;
  const int r0 = u0 >> 3, r1 = u1 >> 3;
  const int sx0 = ((u0 & 7) ^ (r0 & 7)) << 3;   // pre-swizzled source k-offset (elems)
  const int sx1 = ((u1 & 7) ^ (r1 & 7)) << 3;
  const long gar0 = m0 + (r0 >> 6) * 128 + (r0 & 63);
  const long gar1 = m0 + (r1 >> 6) * 128 + (r1 & 63);
  const long gbr0 = n0 + (r0 >> 5) * 64 + (r0 & 31);
  const long gbr1 = n0 + (r1 >> 5) * 64 + (r1 & 31);
  const int dl = w * 512;              // wave-uniform LDS dest (u16), HW adds lane*16B

  // fragment read constants (swizzled k-slot = slot ^ (row&7))
  const int aro = (wm * 64 + il) * 64;
  const int bro = (wn * 32 + il) * 64;
  const int ax = (il & 7) << 3;
  const int ko0 = (q * 8) ^ ax;        // kk=0
  const int ko1 = (32 + q * 8) ^ ax;   // kk=1

  f32x4 acc[8][4] = {};
  bf16x8 af[4], afk[4], bf0[2][2], bf1[2][2];

#define ASP(BUF, MH) (&SH[((BUF) * 2 + (MH)) * 8192])
#define BSP(BUF, NH) (&SH[32768 + ((BUF) * 2 + (NH)) * 8192])
#define STGA(BUF, MH, KT) do { \
    g2l16(A + (gar0 + (MH) * 64) * (long)lda + (KT) * 64 + sx0, ASP(BUF, MH) + dl); \
    g2l16(A + (gar1 + (MH) * 64) * (long)lda + (KT) * 64 + sx1, ASP(BUF, MH) + 4096 + dl); \
  } while (0)
#define STGB(BUF, NH, KT) do { \
    g2l16(Bm + (gbr0 + (NH) * 32) * (long)K + (KT) * 64 + sx0, BSP(BUF, NH) + dl); \
    g2l16(Bm + (gbr1 + (NH) * 32) * (long)K + (KT) * 64 + sx1, BSP(BUF, NH) + 4096 + dl); \
  } while (0)
#define LDAF(BUF, MH) do { \
    _Pragma("unroll") for (int f = 0; f < 4; ++f) { \
      af[f]  = *(const bf16x8*)(ASP(BUF, MH) + aro + f * 1024 + ko0); \
      afk[f] = *(const bf16x8*)(ASP(BUF, MH) + aro + f * 1024 + ko1); \
    } } while (0)
#define LDBF(BUF, NH, BF) do { \
    _Pragma("unroll") for (int j = 0; j < 2; ++j) { \
      BF[j][0] = *(const bf16x8*)(BSP(BUF, NH) + bro + j * 1024 + ko0); \
      BF[j][1] = *(const bf16x8*)(BSP(BUF, NH) + bro + j * 1024 + ko1); \
    } } while (0)
#define MFMAQ(MH, NH, BF) do { \
    _Pragma("unroll") for (int f = 0; f < 4; ++f) { \
      _Pragma("unroll") for (int j = 0; j < 2; ++j) { \
        acc[(MH)*4+f][(NH)*2+j] = __builtin_amdgcn_mfma_f32_16x16x32_bf16(af[f], BF[j][0], acc[(MH)*4+f][(NH)*2+j], 0, 0, 0); \
        acc[(MH)*4+f][(NH)*2+j] = __builtin_amdgcn_mfma_f32_16x16x32_bf16(afk[f], BF[j][1], acc[(MH)*4+f][(NH)*2+j], 0, 0, 0); \
      } } } while (0)
#define BARR() __builtin_amdgcn_s_barrier()
#define WL0() asm volatile("s_waitcnt lgkmcnt(0)" ::: "memory")
#define WV6() asm volatile("s_waitcnt vmcnt(6)" ::: "memory")
#define SBAR0() __builtin_amdgcn_sched_barrier(0)
#define PRIO(x) __builtin_amdgcn_s_setprio(x)

  // prologue: tile0 all 4 half-tiles + tile1 {A0,B0,B1}; vmcnt(6) completes
  // exactly tile0's 8 loads (FIFO), leaving 6 outstanding entering P1.
  STGA(0, 0, 0); STGB(0, 0, 0); STGB(0, 1, 0); STGA(0, 1, 0);
  STGA(1, 0, 1); STGB(1, 0, 1); STGB(1, 1, 1);
  WV6();
  BARR();

  // Steady state FIFO (2 loads/phase): entering P1: 6 outstanding; P4/P8
  // vmcnt(6) completes the 8 oldest = the 4 half-tiles consumed in the next
  // 4 phases. Every stage targets a region whose last read was the previous
  // phase. Reads issued B-first so the compiler's progressive lgkmcnt lets
  // MFMA start after the first 6 reads while the rest drain underneath.
  for (int tt = 0; tt < nt; tt += 2) {
    const int t1 = tt + 1;
    const int t2 = tt + 2 <= ntm1 ? tt + 2 : ntm1;  // tail: valid addr, dead data
    const int t3 = tt + 3 <= ntm1 ? tt + 3 : ntm1;
    // P1: reads B0,A0(buf0); stage A1(buf1,t1)
    LDBF(0, 0, bf0); LDAF(0, 0);
    STGA(1, 1, t1);
    BARR();
    PRIO(1); MFMAQ(0, 0, bf0); PRIO(0);
    SBAR0(); WL0();
    BARR();
    // P2: reads B1(buf0); stage A0(buf0,t2)  [last read P1]
    LDBF(0, 1, bf1);
    STGA(0, 0, t2);
    BARR();
    PRIO(1); MFMAQ(0, 1, bf1); PRIO(0);
    SBAR0(); WL0();
    BARR();
    // P3: reads A1(buf0); stage B0(buf0,t2)  [last read P1]
    LDAF(0, 1);
    STGB(0, 0, t2);
    BARR();
    PRIO(1); MFMAQ(1, 0, bf0); PRIO(0);
    SBAR0(); WL0();
    BARR();
    // P4: regs only; stage B1(buf0,t2)  [last read P2]; counted wait
    STGB(0, 1, t2);
    BARR();
    PRIO(1); MFMAQ(1, 1, bf1); PRIO(0);
    WV6(); BARR();
    // P5: reads B0,A0(buf1); stage A1(buf0,t2)  [last read P3]
    LDBF(1, 0, bf0); LDAF(1, 0);
    STGA(0, 1, t2);
    BARR();
    PRIO(1); MFMAQ(0, 0, bf0); PRIO(0);
    SBAR0(); WL0();
    BARR();
    // P6: reads B1(buf1); stage A0(buf1,t3)  [last read P5]
    LDBF(1, 1, bf1);
    STGA(1, 0, t3);
    BARR();
    PRIO(1); MFMAQ(0, 1, bf1); PRIO(0);
    SBAR0(); WL0();
    BARR();
    // P7: reads A1(buf1); stage B0(buf1,t3)  [last read P5]
    LDAF(1, 1);
    STGB(1, 0, t3);
    BARR();
    PRIO(1); MFMAQ(1, 0, bf0); PRIO(0);
    SBAR0(); WL0();
    BARR();
    // P8: regs only; stage B1(buf1,t3)  [last read P6]; counted wait
    STGB(1, 1, t3);
    BARR();
    PRIO(1); MFMAQ(1, 1, bf1); PRIO(0);
    WV6(); BARR();
  }

  asm volatile("s_waitcnt vmcnt(0)" ::: "memory");  // drain tail stages (they DMA into SH)
  __syncthreads();

  // ---- epilogue: stage C tile in LDS, emit full-line coalesced stores ----
  if (C32) {
    // fp32: two 128-row halves (128*256*4B = 128KB each). wm==h waves own half h.
    float* Cf = (float*)SH;
#pragma unroll
    for (int h = 0; h < 2; ++h) {
      if (wm == h) {
#pragma unroll
        for (int ni = 0; ni < 4; ++ni) {
          const int ccol = wn * 64 + ni * 16 + il;
          const float bv = bias ? bias[n0 + ccol] : 0.0f;
#pragma unroll
          for (int mi = 0; mi < 8; ++mi) {
#pragma unroll
            for (int r = 0; r < 4; ++r) {
              const int crow = (mi >> 2) * 64 + (mi & 3) * 16 + q * 4 + r;
              const int byte = (crow * 1024 + ccol * 4) ^ (((crow >> 2) & 1) << 6);
              *(float*)((char*)Cf + byte) = acc[mi][ni][r] + bv;
            }
          }
        }
      }
      __syncthreads();
#pragma unroll
      for (int i = 0; i < 16; ++i) {
        const int u = i * 512 + tid;
        const int crow = u >> 6, c16 = u & 63;
        const int byte = (crow * 1024 + c16 * 16) ^ (((crow >> 2) & 1) << 6);
        float4 v = *(const float4*)((char*)Cf + byte);
        *(float4*)(C32 + (m0 + h * 128 + crow) * N + n0 + c16 * 4) = v;
      }
      __syncthreads();
    }
  } else {
    // bf16: whole 256x256 tile = 128KB.
    u16* Cs = (u16*)SH;
#pragma unroll
    for (int ni = 0; ni < 4; ++ni) {
      const int ccol = wn * 64 + ni * 16 + il;
      const float bv = bias ? bias[n0 + ccol] : 0.0f;
#pragma unroll
      for (int mi = 0; mi < 8; ++mi) {
#pragma unroll
        for (int r = 0; r < 4; ++r) {
          const int crow = wm * 128 + (mi >> 2) * 64 + (mi & 3) * 16 + q * 4 + r;
          const int byte = (crow * 512 + ccol * 2) ^ (((crow >> 2) & 3) << 5);
          *(u16*)((char*)Cs + byte) = f2bf(acc[mi][ni][r] + bv);
        }
      }
    }
    __syncthreads();
#pragma unroll
    for (int i = 0; i < 16; ++i) {
      const int u = i * 512 + tid;
      const int crow = u >> 5, c16 = u & 31;
      const int byte = (crow * 512 + c16 * 16) ^ (((crow >> 2) & 3) << 5);
      uint4 v = *(const uint4*)((char*)Cs + byte);
      *(uint4*)(C16 + (m0 + crow) * N + n0 + c16 * 8) = v;
    }
  }
#undef ASP
#undef BSP
#undef STGA
#undef STGB
#undef LDAF
#undef LDBF
#undef MFMAQ
#undef BARR
#undef WL0
#undef WV6
#undef SBAR0
#undef PRIO
}

// scores[r] = mean(tanh(y[r, :])) over D=1024 (y bf16, bias already added)
__global__ __launch_bounds__(256) void scores_k(const u16* __restrict__ y,
                                                float* __restrict__ scores)
{
  const int lane = threadIdx.x & 63;
  const long r = (long)blockIdx.x * 4 + (threadIdx.x >> 6);
  const u16* p = y + r * D_ + lane * 16;
  uint4 v0 = *(const uint4*)p;
  uint4 v1 = *(const uint4*)(p + 8);
  union { uint4 v; u16 s[8]; } a, c;
  a.v = v0; c.v = v1;
  float s = 0.f;
#pragma unroll
  for (int e = 0; e < 8; ++e) s += tanhf(b2f(a.s[e]));
#pragma unroll
  for (int e = 0; e < 8; ++e) s += tanhf(b2f(c.s[e]));
#pragma unroll
  for (int o = 32; o; o >>= 1) s += __shfl_xor(s, o, 64);
  if (lane == 0) scores[r] = s * (1.0f / 1024.0f);
}

// per-window softmax over scores -> weighted sum of fp32 x rows -> summaries
__global__ __launch_bounds__(256) void summar_k(const float* __restrict__ x,
                                                const float* __restrict__ scores,
                                                float* __restrict__ summ)
{
  __shared__ float wts[64];
  const int tid = threadIdx.x;
  const int b = blockIdx.x >> 6, n = blockIdx.x & 63;
  if (tid < 64) {
    float v = scores[(long)b * T_ + n * 64 + tid];
    float mx = v;
#pragma unroll
    for (int o = 32; o; o >>= 1) mx = fmaxf(mx, __shfl_xor(mx, o, 64));
    float e = __expf(v - mx);
    float s = e;
#pragma unroll
    for (int o = 32; o; o >>= 1) s += __shfl_xor(s, o, 64);
    wts[tid] = e / s;
  }
  __syncthreads();
  const int d0 = tid * 4;
  const float* xp = x + ((long)b * T_ + n * 64) * D_ + d0;
  float a0 = 0, a1 = 0, a2 = 0, a3 = 0;
#pragma unroll 4
  for (int wd = 0; wd < 64; ++wd) {
    float4 v = *(const float4*)(xp + (long)wd * D_);
    float wv = wts[wd];
    a0 += wv * v.x; a1 += wv * v.y; a2 += wv * v.z; a3 += wv * v.w;
  }
  *(float4*)(summ + ((long)b * NW_ + n) * D_ + d0) = make_float4(a0, a1, a2, a3);
}

// cross-summary attention: cs_out[b,n,:] = softmax(summ[n]·jit[m]/32)_m @ jit
__global__ __launch_bounds__(256) void cross_k(const float* __restrict__ summ,
                                               const int* __restrict__ jitter,
                                               float* __restrict__ cso)
{
  __shared__ float sm[64], pm[64];
  __shared__ int jidx[64];
  const int tid = threadIdx.x;
  const int b = blockIdx.x >> 6, n = blockIdx.x & 63;
  if (tid < 64) jidx[tid] = jitter[tid];
  __syncthreads();
  const int m = tid >> 2, part = tid & 3;
  const float* sn = summ + ((long)b * NW_ + n) * D_;
  const float* sj = summ + ((long)b * NW_ + jidx[m]) * D_;
  float p = 0.f;
  for (int d = part * 256; d < part * 256 + 256; d += 4) {
    float4 aa = *(const float4*)(sn + d);
    float4 bb = *(const float4*)(sj + d);
    p += aa.x * bb.x + aa.y * bb.y + aa.z * bb.z + aa.w * bb.w;
  }
  p += __shfl_xor(p, 1, 64);
  p += __shfl_xor(p, 2, 64);
  if (part == 0) sm[m] = p * (1.0f / 32.0f);
  __syncthreads();
  if (tid < 64) {
    float v = sm[tid], mx = v;
#pragma unroll
    for (int o = 32; o; o >>= 1) mx = fmaxf(mx, __shfl_xor(mx, o, 64));
    float e = __expf(v - mx), s = e;
#pragma unroll
    for (int o = 32; o; o >>= 1) s += __shfl_xor(s, o, 64);
    pm[tid] = e / s;
  }
  __syncthreads();
  const int d0 = tid * 4;
  float a0 = 0, a1 = 0, a2 = 0, a3 = 0;
  for (int mm = 0; mm < 64; ++mm) {
    const float* sr = summ + ((long)b * NW_ + jidx[mm]) * D_ + d0;
    float wv = pm[mm];
    float4 vv = *(const float4*)sr;
    a0 += wv * vv.x; a1 += wv * vv.y; a2 += wv * vv.z; a3 += wv * vv.w;
  }
  *(float4*)(cso + ((long)b * NW_ + n) * D_ + d0) = make_float4(a0, a1, a2, a3);
}

// windowed attention, one block per (b,h,n); writes final = local + 0.25*cs
// IN-PLACE into the q-slice of qkv (each block writes only the region it reads).
__global__ __launch_bounds__(256) void attn_win(u16* qkv,
                                                const float* __restrict__ cso)
{
  __shared__ u16 Qs[64 * 72], Ks[64 * 72], Vt[64 * 72], Ps[64 * 72];
  unsigned* Vt32 = (unsigned*)Vt;          // word stride 36/row (byte 144, b128-aligned)
  const int tid = threadIdx.x;
  const int lane = tid & 63;
  const int w = tid >> 6;
  const int q = lane >> 4, il = lane & 15;
  const int bid = blockIdx.x;
  const int n = bid & 63;
  const int h = (bid >> 6) & 15;
  const int b = bid >> 10;
  const long rowbase = (long)b * T_ + n * 64;

#pragma unroll
  for (int i = 0; i < 2; ++i) {
    int u = i * 256 + tid;
    int row = u >> 3, cp = u & 7;
    const u16* src = qkv + (rowbase + row) * 3072 + h * 64 + cp * 8;
    uint4 qv = *(const uint4*)src;
    uint4 kv = *(const uint4*)(src + 1024);
    uint4 vv = *(const uint4*)(src + 2048);
    *(uint4*)&Qs[row * 72 + cp * 8] = qv;
    *(uint4*)&Ks[row * 72 + cp * 8] = kv;
    // V transpose via row-pair packing: tid/tid^8 hold rows 2p,2p+1 (same cols).
    union { uint4 v; unsigned u[4]; } mine, part;
    mine.v = vv;
#pragma unroll
    for (int m = 0; m < 4; ++m) part.u[m] = __shfl_xor(mine.u[m], 8, 64);
    const bool even = ((row & 1) == 0);
    const int p = row >> 1;
#pragma unroll
    for (int m = 0; m < 4; ++m) {
      unsigned word = even ? ((mine.u[m] & 0xffffu) | (part.u[m] << 16))
                           : ((part.u[m] >> 16)     | (mine.u[m] & 0xffff0000u));
      int c = cp * 8 + 2 * m + (even ? 0 : 1);     // Vt row = V column
      Vt32[c * 36 + p] = word;                     // u32 store: 4 stores vs 8, ~8-way
    }
  }
  __syncthreads();

  // S = Q K^T : wave w owns rows [16w,16w+16), 4 col-tiles of 16
  f32x4 sacc[4] = {};
#pragma unroll
  for (int ks = 0; ks < 2; ++ks) {
    bf16x8 aq = *(const bf16x8*)&Qs[(w * 16 + il) * 72 + ks * 32 + q * 8];
#pragma unroll
    for (int ct = 0; ct < 4; ++ct) {
      bf16x8 bk = *(const bf16x8*)&Ks[(ct * 16 + il) * 72 + ks * 32 + q * 8];
      sacc[ct] = __builtin_amdgcn_mfma_f32_16x16x32_bf16(aq, bk, sacc[ct], 0, 0, 0);
    }
  }

  // row softmax: row = 16w+4q+r; its 64 cols live in this quad (16 il x 4 tiles)
#pragma unroll
  for (int r = 0; r < 4; ++r) {
    float s0 = sacc[0][r] * 0.125f, s1 = sacc[1][r] * 0.125f,
          s2 = sacc[2][r] * 0.125f, s3 = sacc[3][r] * 0.125f;
    float mx = fmaxf(fmaxf(s0, s1), fmaxf(s2, s3));
#pragma unroll
    for (int o = 1; o < 16; o <<= 1) mx = fmaxf(mx, __shfl_xor(mx, o, 64));
    float e0 = __expf(s0 - mx), e1 = __expf(s1 - mx),
          e2 = __expf(s2 - mx), e3 = __expf(s3 - mx);
    float sum = e0 + e1 + e2 + e3;
#pragma unroll
    for (int o = 1; o < 16; o <<= 1) sum += __shfl_xor(sum, o, 64);
    float inv = 1.0f / sum;
    int prow = w * 16 + q * 4 + r;
    Ps[prow * 72 + 0 * 16 + il] = f2bf(e0 * inv);
    Ps[prow * 72 + 1 * 16 + il] = f2bf(e1 * inv);
    Ps[prow * 72 + 2 * 16 + il] = f2bf(e2 * inv);
    Ps[prow * 72 + 3 * 16 + il] = f2bf(e3 * inv);
  }
  __syncthreads();

  // O = P V : A-frag from Ps rows, B-frag from Vt rows (= V columns)
  f32x4 oacc[4] = {};
#pragma unroll
  for (int ks = 0; ks < 2; ++ks) {
    bf16x8 ap = *(const bf16x8*)&Ps[(w * 16 + il) * 72 + ks * 32 + q * 8];
#pragma unroll
    for (int dt = 0; dt < 4; ++dt) {
      bf16x8 bv = *(const bf16x8*)&Vt[(dt * 16 + il) * 72 + ks * 32 + q * 8];
      oacc[dt] = __builtin_amdgcn_mfma_f32_16x16x32_bf16(ap, bv, oacc[dt], 0, 0, 0);
    }
  }

  const float* cs = cso + ((long)b * NW_ + n) * D_ + h * 64;
#pragma unroll
  for (int dt = 0; dt < 4; ++dt) {
    int col = dt * 16 + il;
    float cadd = 0.25f * cs[col];
#pragma unroll
    for (int r = 0; r < 4; ++r) {
      int row = w * 16 + q * 4 + r;
      qkv[(rowbase + row) * 3072 + h * 64 + col] = f2bf(oacc[dt][r] + cadd);
    }
  }
}

extern "C" void kernel_launch(void* const* d_in, const int* in_sizes, int n_in,
                              void* d_out, int out_size, void* d_ws, size_t ws_size,
                              hipStream_t stream)
{
  (void)in_sizes; (void)n_in; (void)out_size; (void)ws_size;
  const float* x      = (const float*)d_in[0];
  const float* Wqkv   = (const float*)d_in[1];
  const float* Wout   = (const float*)d_in[2];
  const float* bout   = (const float*)d_in[3];
  const float* Wcross = (const float*)d_in[4];
  const float* bcross = (const float*)d_in[5];
  const int*   jitter = (const int*)d_in[6];
  float* out = (float*)d_out;

  // ws layout (bytes), total 144,769,024 (round-2 verified footprint):
  char* ws = (char*)d_ws;
  u16*   qkv    = (u16*)ws;                        // 100,663,296 (y bf16 aliases @0)
  u16*   y      = (u16*)ws;
  u16*   xb     = (u16*)(ws + 100663296);          // 33,554,432
  u16*   wqkvb  = (u16*)(ws + 134217728);          //  6,291,456
  u16*   wtmp   = (u16*)(ws + 140509184);          //  2,097,152 (Wcross, then Wout)
  float* scores = (float*)(ws + 142606336);        //     65,536
  float* summ   = (float*)(ws + 142671872);        //  1,048,576
  float* cso    = (float*)(ws + 143720448);        //  1,048,576

  dim3 blk(256);
  dim3 gblk(512);
  // fused input casts: x->xb, Wqkv->wqkvb, Wcross->wtmp
  cvt3_k<<<20480, blk, 0, stream>>>(x, xb, Wqkv, wqkvb, Wcross, wtmp);
  // cross-score path (grid 4x64 = 256 blocks, %8==0)
  gemm256<<<dim3(4, 64), gblk, 0, stream>>>(xb, wtmp, y, nullptr, bcross, 16384, 1024, 1024, 1024);
  cvt_k<<<1024, blk, 0, stream>>>(Wout, wtmp, 1048576L);   // wtmp free after cross gemm
  scores_k<<<4096, blk, 0, stream>>>(y, scores);
  summar_k<<<256, blk, 0, stream>>>(x, scores, summ);
  cross_k<<<256, blk, 0, stream>>>(summ, jitter, cso);
  // main path (y dead now; qkv overwrites it) (grid 12x64 = 768 blocks, %8==0)
  gemm256<<<dim3(12, 64), gblk, 0, stream>>>(xb, wqkvb, qkv, nullptr, nullptr, 16384, 3072, 1024, 1024);
  attn_win<<<4096, blk, 0, stream>>>(qkv, cso);            // in-place -> q-slice
  gemm256<<<dim3(4, 64), gblk, 0, stream>>>(qkv, wtmp, nullptr, out, bout, 16384, 1024, 1024, 3072);
}